// Round 1
// baseline (1302.200 us; speedup 1.0000x reference)
//
#include <hip/hip_runtime.h>
#include <math.h>

#define NSLOPE 0.2f

__device__ __forceinline__ float lrelu(float v) { return v > 0.f ? v : NSLOPE * v; }

// ---------------------------------------------------------------- flag detect
// If edge_index arrives as int64 (reference dtype), every u64 word is < 2^32.
// If it arrives as int32, u64 words combine two random node ids -> huge.
__global__ void k_flag(const unsigned long long* __restrict__ p, int* __restrict__ flag) {
    if (blockIdx.x == 0 && threadIdx.x == 0) {
        int ok = 1;
        for (int i = 0; i < 256; i++)
            if (p[i] >= (1ull << 32)) { ok = 0; break; }
        *flag = ok;  // 1 = int64 layout, 0 = int32 layout
    }
}

__device__ __forceinline__ void load_edge(const void* ei, long long E, long long i, int fl,
                                          int& u, int& v) {
    if (fl) {
        const long long* p = (const long long*)ei;
        u = (int)p[i]; v = (int)p[E + i];
    } else {
        const int* p = (const int*)ei;
        u = p[i]; v = p[E + i];
    }
}

// ---------------------------------------------------------------- node prep
// h1 = x @ W1 (3->16) for both directions, attention scores, zero counters.
__global__ void k_prep(const float* __restrict__ x,
                       const float* __restrict__ W1, const float* __restrict__ as1, const float* __restrict__ ad1,
                       const float* __restrict__ W1r, const float* __restrict__ as1r, const float* __restrict__ ad1r,
                       float* __restrict__ h1f, float* __restrict__ h1r,
                       float* __restrict__ s1sf, float* __restrict__ s1df,
                       float* __restrict__ s1sr, float* __restrict__ s1dr,
                       int* __restrict__ degf, int* __restrict__ degr,
                       int* __restrict__ curf, int* __restrict__ curr, int N) {
    int i = blockIdx.x * blockDim.x + threadIdx.x;
    if (i >= N) return;
    degf[i] = 0; degr[i] = 0; curf[i] = 0; curr[i] = 0;
    float x0 = x[3 * i], x1 = x[3 * i + 1], x2 = x[3 * i + 2];
    float ssf = 0.f, sdf = 0.f, ssr = 0.f, sdr = 0.f;
#pragma unroll
    for (int k = 0; k < 16; k++) {
        float hf = x0 * W1[k] + x1 * W1[16 + k] + x2 * W1[32 + k];
        h1f[16 * i + k] = hf;
        ssf += hf * as1[k];
        sdf += hf * ad1[k];
        float hr = x0 * W1r[k] + x1 * W1r[16 + k] + x2 * W1r[32 + k];
        h1r[16 * i + k] = hr;
        ssr += hr * as1r[k];
        sdr += hr * ad1r[k];
    }
    s1sf[i] = ssf; s1df[i] = sdf; s1sr[i] = ssr; s1dr[i] = sdr;
}

// ---------------------------------------------------------------- degree hist
__global__ void k_hist(const void* __restrict__ ei, long long E, const int* __restrict__ flag,
                       int* __restrict__ degf, int* __restrict__ degr) {
    long long i = blockIdx.x * (long long)blockDim.x + threadIdx.x;
    if (i >= E) return;
    int u, v;
    load_edge(ei, E, i, *flag, u, v);
    atomicAdd(&degf[v], 1);  // fwd: dst = e1
    atomicAdd(&degr[u], 1);  // rev: dst = e0
}

// ---------------------------------------------------------------- excl. scan
// Single block of 1024 threads, scans both degree arrays to offsets.
__global__ void k_scan(const int* __restrict__ degf, int* __restrict__ offf,
                       const int* __restrict__ degr, int* __restrict__ offr, int N) {
    __shared__ int sm[1024];
    int t = threadIdx.x;
    int chunk = (N + 1023) >> 10;
    for (int a = 0; a < 2; a++) {
        const int* deg = a ? degr : degf;
        int* off = a ? offr : offf;
        int begin = t * chunk; if (begin > N) begin = N;
        int end = begin + chunk; if (end > N) end = N;
        int s = 0;
        for (int i = begin; i < end; i++) s += deg[i];
        __syncthreads();
        sm[t] = s;
        __syncthreads();
        for (int od = 1; od < 1024; od <<= 1) {
            int tmp = (t >= od) ? sm[t - od] : 0;
            __syncthreads();
            sm[t] += tmp;
            __syncthreads();
        }
        int base = sm[t] - s;  // exclusive prefix
        for (int i = begin; i < end; i++) { off[i] = base; base += deg[i]; }
    }
}

// ---------------------------------------------------------------- CSR fill
__global__ void k_fill(const void* __restrict__ ei, long long E, const int* __restrict__ flag,
                       const int* __restrict__ offf, int* __restrict__ curf, int* __restrict__ csrf,
                       const int* __restrict__ offr, int* __restrict__ curr, int* __restrict__ csrr) {
    long long i = blockIdx.x * (long long)blockDim.x + threadIdx.x;
    if (i >= E) return;
    int u, v;
    load_edge(ei, E, i, *flag, u, v);
    int p = atomicAdd(&curf[v], 1);
    csrf[offf[v] + p] = u;
    int q = atomicAdd(&curr[u], 1);
    csrr[offr[u] + q] = v;
}

// ---------------------------------------------------------------- conv1 agg
// Online softmax over in-edges (+ implicit self loop), fused relu + W2 proj.
__global__ void k_agg1(const float* __restrict__ h1f, const float* __restrict__ s1sf, const float* __restrict__ s1df,
                       const float* __restrict__ h1r, const float* __restrict__ s1sr, const float* __restrict__ s1dr,
                       const int* __restrict__ offf, const int* __restrict__ degf, const int* __restrict__ csrf,
                       const int* __restrict__ offr, const int* __restrict__ degr, const int* __restrict__ csrr,
                       const float* __restrict__ b1, const float* __restrict__ W2,
                       const float* __restrict__ as2, const float* __restrict__ ad2,
                       const float* __restrict__ b1r, const float* __restrict__ W2r,
                       const float* __restrict__ as2r, const float* __restrict__ ad2r,
                       float2* __restrict__ p2f, float* __restrict__ s2df,
                       float2* __restrict__ p2r, float* __restrict__ s2dr, int N) {
    int v = blockIdx.x * blockDim.x + threadIdx.x;
    if (v >= N) return;
    // ---- forward direction
    {
        float sd = s1df[v];
        float m = -INFINITY, d = 0.f;
        float acc[16];
#pragma unroll
        for (int k = 0; k < 16; k++) acc[k] = 0.f;
        int st = offf[v], n = degf[v];
        for (int j = -1; j < n; j++) {
            int u = (j < 0) ? v : csrf[st + j];
            float e = lrelu(s1sf[u] + sd);
            float mn = fmaxf(m, e);
            float sc = __expf(m - mn);
            float du = __expf(e - mn);
            d = d * sc + du;
            const float4* hp = (const float4*)(h1f + 16 * u);
#pragma unroll
            for (int r = 0; r < 4; r++) {
                float4 h4 = hp[r];
                acc[4 * r + 0] = acc[4 * r + 0] * sc + du * h4.x;
                acc[4 * r + 1] = acc[4 * r + 1] * sc + du * h4.y;
                acc[4 * r + 2] = acc[4 * r + 2] * sc + du * h4.z;
                acc[4 * r + 3] = acc[4 * r + 3] * sc + du * h4.w;
            }
            m = mn;
        }
        float inv = 1.f / (d + 1e-16f);
        float h2 = 0.f;
#pragma unroll
        for (int k = 0; k < 16; k++) {
            float o = fmaxf(acc[k] * inv + b1[k], 0.f);
            h2 += o * W2[k];
        }
        p2f[v] = make_float2(h2, h2 * as2[0]);
        s2df[v] = h2 * ad2[0];
    }
    // ---- reverse direction
    {
        float sd = s1dr[v];
        float m = -INFINITY, d = 0.f;
        float acc[16];
#pragma unroll
        for (int k = 0; k < 16; k++) acc[k] = 0.f;
        int st = offr[v], n = degr[v];
        for (int j = -1; j < n; j++) {
            int u = (j < 0) ? v : csrr[st + j];
            float e = lrelu(s1sr[u] + sd);
            float mn = fmaxf(m, e);
            float sc = __expf(m - mn);
            float du = __expf(e - mn);
            d = d * sc + du;
            const float4* hp = (const float4*)(h1r + 16 * u);
#pragma unroll
            for (int r = 0; r < 4; r++) {
                float4 h4 = hp[r];
                acc[4 * r + 0] = acc[4 * r + 0] * sc + du * h4.x;
                acc[4 * r + 1] = acc[4 * r + 1] * sc + du * h4.y;
                acc[4 * r + 2] = acc[4 * r + 2] * sc + du * h4.z;
                acc[4 * r + 3] = acc[4 * r + 3] * sc + du * h4.w;
            }
            m = mn;
        }
        float inv = 1.f / (d + 1e-16f);
        float h2 = 0.f;
#pragma unroll
        for (int k = 0; k < 16; k++) {
            float o = fmaxf(acc[k] * inv + b1r[k], 0.f);
            h2 += o * W2r[k];
        }
        p2r[v] = make_float2(h2, h2 * as2r[0]);
        s2dr[v] = h2 * ad2r[0];
    }
}

// ---------------------------------------------------------------- conv2 agg + combine
__global__ void k_agg2(const float2* __restrict__ p2f, const float* __restrict__ s2df,
                       const int* __restrict__ offf, const int* __restrict__ degf, const int* __restrict__ csrf,
                       const float2* __restrict__ p2r, const float* __restrict__ s2dr,
                       const int* __restrict__ offr, const int* __restrict__ degr, const int* __restrict__ csrr,
                       const float* __restrict__ b2, const float* __restrict__ b2r,
                       float* __restrict__ out, int N) {
    int v = blockIdx.x * blockDim.x + threadIdx.x;
    if (v >= N) return;
    float of;
    {
        float sd = s2df[v];
        float m = -INFINITY, d = 0.f, a = 0.f;
        int st = offf[v], n = degf[v];
        for (int j = -1; j < n; j++) {
            int u = (j < 0) ? v : csrf[st + j];
            float2 t = p2f[u];
            float e = lrelu(t.y + sd);
            float mn = fmaxf(m, e);
            float sc = __expf(m - mn);
            float du = __expf(e - mn);
            d = d * sc + du;
            a = a * sc + du * t.x;
            m = mn;
        }
        of = a / (d + 1e-16f) + b2[0];
    }
    float orv;
    {
        float sd = s2dr[v];
        float m = -INFINITY, d = 0.f, a = 0.f;
        int st = offr[v], n = degr[v];
        for (int j = -1; j < n; j++) {
            int u = (j < 0) ? v : csrr[st + j];
            float2 t = p2r[u];
            float e = lrelu(t.y + sd);
            float mn = fmaxf(m, e);
            float sc = __expf(m - mn);
            float du = __expf(e - mn);
            d = d * sc + du;
            a = a * sc + du * t.x;
            m = mn;
        }
        orv = a / (d + 1e-16f) + b2r[0];
    }
    out[v] = 0.5f * (of + orv);
}

// ================================================================ launch
extern "C" void kernel_launch(void* const* d_in, const int* in_sizes, int n_in,
                              void* d_out, int out_size, void* d_ws, size_t ws_size,
                              hipStream_t stream) {
    const float* x   = (const float*)d_in[0];
    const void*  ei  = d_in[1];
    const float* W1  = (const float*)d_in[2];
    const float* as1 = (const float*)d_in[3];
    const float* ad1 = (const float*)d_in[4];
    const float* b1  = (const float*)d_in[5];
    const float* W2  = (const float*)d_in[6];
    const float* as2 = (const float*)d_in[7];
    const float* ad2 = (const float*)d_in[8];
    const float* b2  = (const float*)d_in[9];
    const float* W1r  = (const float*)d_in[10];
    const float* as1r = (const float*)d_in[11];
    const float* ad1r = (const float*)d_in[12];
    const float* b1r  = (const float*)d_in[13];
    const float* W2r  = (const float*)d_in[14];
    const float* as2r = (const float*)d_in[15];
    const float* ad2r = (const float*)d_in[16];
    const float* b2r  = (const float*)d_in[17];

    const int N = in_sizes[0] / 3;
    const long long E = in_sizes[1] / 2;

    char* w = (char*)d_ws;
    size_t o = 0;
    auto A = [&](size_t bytes) { o = (o + 255) & ~(size_t)255; size_t r = o; o += bytes; return r; };
    size_t oFlag = A(64);
    size_t oH1f  = A(sizeof(float) * 16 * N);
    size_t oH1r  = A(sizeof(float) * 16 * N);
    size_t oS1sf = A(sizeof(float) * N);
    size_t oS1df = A(sizeof(float) * N);
    size_t oS1sr = A(sizeof(float) * N);
    size_t oS1dr = A(sizeof(float) * N);
    size_t oP2f  = A(sizeof(float2) * N);
    size_t oS2df = A(sizeof(float) * N);
    size_t oP2r  = A(sizeof(float2) * N);
    size_t oS2dr = A(sizeof(float) * N);
    size_t oDegf = A(sizeof(int) * N);
    size_t oDegr = A(sizeof(int) * N);
    size_t oOfff = A(sizeof(int) * (N + 1));
    size_t oOffr = A(sizeof(int) * (N + 1));
    size_t oCurf = A(sizeof(int) * N);
    size_t oCurr = A(sizeof(int) * N);
    size_t oCsrf = A(sizeof(int) * E);
    size_t oCsrr = A(sizeof(int) * E);
    (void)ws_size; (void)n_in; (void)out_size;

    int*    flag = (int*)(w + oFlag);
    float*  h1f  = (float*)(w + oH1f);
    float*  h1r  = (float*)(w + oH1r);
    float*  s1sf = (float*)(w + oS1sf);
    float*  s1df = (float*)(w + oS1df);
    float*  s1sr = (float*)(w + oS1sr);
    float*  s1dr = (float*)(w + oS1dr);
    float2* p2f  = (float2*)(w + oP2f);
    float*  s2df = (float*)(w + oS2df);
    float2* p2r  = (float2*)(w + oP2r);
    float*  s2dr = (float*)(w + oS2dr);
    int* degf = (int*)(w + oDegf);
    int* degr = (int*)(w + oDegr);
    int* offf = (int*)(w + oOfff);
    int* offr = (int*)(w + oOffr);
    int* curf = (int*)(w + oCurf);
    int* curr = (int*)(w + oCurr);
    int* csrf = (int*)(w + oCsrf);
    int* csrr = (int*)(w + oCsrr);

    dim3 blk(256);
    dim3 gN((N + 255) / 256);
    dim3 gE((unsigned)((E + 255) / 256));

    k_flag<<<1, 64, 0, stream>>>((const unsigned long long*)ei, flag);
    k_prep<<<gN, blk, 0, stream>>>(x, W1, as1, ad1, W1r, as1r, ad1r,
                                   h1f, h1r, s1sf, s1df, s1sr, s1dr,
                                   degf, degr, curf, curr, N);
    k_hist<<<gE, blk, 0, stream>>>(ei, E, flag, degf, degr);
    k_scan<<<1, 1024, 0, stream>>>(degf, offf, degr, offr, N);
    k_fill<<<gE, blk, 0, stream>>>(ei, E, flag, offf, curf, csrf, offr, curr, csrr);
    k_agg1<<<gN, blk, 0, stream>>>(h1f, s1sf, s1df, h1r, s1sr, s1dr,
                                   offf, degf, csrf, offr, degr, csrr,
                                   b1, W2, as2, ad2, b1r, W2r, as2r, ad2r,
                                   p2f, s2df, p2r, s2dr, N);
    k_agg2<<<gN, blk, 0, stream>>>(p2f, s2df, offf, degf, csrf,
                                   p2r, s2dr, offr, degr, csrr,
                                   b2, b2r, (float*)d_out, N);
}